// Round 4
// baseline (83.938 us; speedup 1.0000x reference)
//
#include <hip/hip_runtime.h>

#define NCELLS 512
#define DIM    64
#define ROWS_PER_BLOCK 32
#define NROWS  8192

// One 1024-thread block per CU (grid=256). Full pc (64k x 512 cells = 128 KiB)
// staged into LDS ONCE (R2/R3 lesson: chunked re-staging + barrier phases, not
// occupancy or LDS BW, held the kernel at ~31 us).
// Layout: pcT[k][phys_col], phys_col=(cell+4k)&511 — staging writes land on
// consecutive banks (2-way = free), inner-loop reads are contiguous b128,
// conflict-free.
// Row split across a wave PAIR: lane L=tid&127 owns cells 4L..4L+3 -> one
// ds_read_b128 feeds 32 VALU (4 rows x 4 cells x sub+abs-add). Per-CU model:
// VALU 6.8 us, LDS-read 5.1 us, staging ~1.5 us once.
// Accumulators are named float4s — indexed local arrays spill to scratch (R1).
__global__ __launch_bounds__(1024, 4)
void placecells_kernel(const float* __restrict__ x,
                       const float* __restrict__ pc,
                       float* __restrict__ out)
{
    __shared__ float pcT[DIM * NCELLS];   // 128 KiB
    __shared__ float redMin[64];          // [pair][wave][row]
    __shared__ float redSum[64];

    const int tid = (int)threadIdx.x;
    const int l   = tid & 63;                 // lane in wave
    const int L   = tid & 127;                // lane in pair
    const int w1  = (tid >> 6) & 1;           // wave within pair
    const int p   = __builtin_amdgcn_readfirstlane(tid >> 7);  // pair 0..7 (wave-uniform)
    const int rowBase = (int)blockIdx.x * ROWS_PER_BLOCK + p * 4;

    // ---- stage full pc -> LDS (transposed + rotated), once ----
    #pragma unroll
    for (int i = 0; i < 8; ++i) {
        int idx = i * 1024 + tid;
        int cl  = idx & 511;                  // cell
        int k4  = idx >> 9;                   // k-quad 0..15
        float4 v = *(const float4*)(pc + cl * DIM + k4 * 4);
        int k0 = k4 * 4;
        pcT[(k0 + 0) * NCELLS + ((cl + 4 * (k0 + 0)) & 511)] = v.x;
        pcT[(k0 + 1) * NCELLS + ((cl + 4 * (k0 + 1)) & 511)] = v.y;
        pcT[(k0 + 2) * NCELLS + ((cl + 4 * (k0 + 2)) & 511)] = v.z;
        pcT[(k0 + 3) * NCELLS + ((cl + 4 * (k0 + 3)) & 511)] = v.w;
    }
    __syncthreads();

    // ---- main loop: 4 rows x 4 cells per lane, k = 0..63 ----
    float4 a0{0,0,0,0}, a1{0,0,0,0}, a2{0,0,0,0}, a3{0,0,0,0};

    #pragma unroll 4
    for (int k4 = 0; k4 < 16; ++k4) {
        // wave-uniform x tiles -> scalar loads
        float4 xv0 = *(const float4*)(x + (rowBase + 0) * DIM + k4 * 4);
        float4 xv1 = *(const float4*)(x + (rowBase + 1) * DIM + k4 * 4);
        float4 xv2 = *(const float4*)(x + (rowBase + 2) * DIM + k4 * 4);
        float4 xv3 = *(const float4*)(x + (rowBase + 3) * DIM + k4 * 4);
        #pragma unroll
        for (int j = 0; j < 4; ++j) {
            const int k = k4 * 4 + j;
            float4 pv = *(const float4*)(&pcT[k * NCELLS + ((4 * L + 4 * k) & 511)]);
            float x0 = (j == 0) ? xv0.x : (j == 1) ? xv0.y : (j == 2) ? xv0.z : xv0.w;
            float x1 = (j == 0) ? xv1.x : (j == 1) ? xv1.y : (j == 2) ? xv1.z : xv1.w;
            float x2 = (j == 0) ? xv2.x : (j == 1) ? xv2.y : (j == 2) ? xv2.z : xv2.w;
            float x3 = (j == 0) ? xv3.x : (j == 1) ? xv3.y : (j == 2) ? xv3.z : xv3.w;
            a0.x += fabsf(x0 - pv.x); a0.y += fabsf(x0 - pv.y);
            a0.z += fabsf(x0 - pv.z); a0.w += fabsf(x0 - pv.w);
            a1.x += fabsf(x1 - pv.x); a1.y += fabsf(x1 - pv.y);
            a1.z += fabsf(x1 - pv.z); a1.w += fabsf(x1 - pv.w);
            a2.x += fabsf(x2 - pv.x); a2.y += fabsf(x2 - pv.y);
            a2.z += fabsf(x2 - pv.z); a2.w += fabsf(x2 - pv.w);
            a3.x += fabsf(x3 - pv.x); a3.y += fabsf(x3 - pv.y);
            a3.z += fabsf(x3 - pv.z); a3.w += fabsf(x3 - pv.w);
        }
    }

    // ---- softmax: each row spans a wave pair (128 lanes) ----
    auto wmin = [&](float v) {
        #pragma unroll
        for (int off = 32; off > 0; off >>= 1) v = fminf(v, __shfl_xor(v, off, 64));
        return v;
    };
    auto wsum = [&](float v) {
        #pragma unroll
        for (int off = 32; off > 0; off >>= 1) v += __shfl_xor(v, off, 64);
        return v;
    };

    float m0 = wmin(fminf(fminf(a0.x, a0.y), fminf(a0.z, a0.w)));
    float m1 = wmin(fminf(fminf(a1.x, a1.y), fminf(a1.z, a1.w)));
    float m2 = wmin(fminf(fminf(a2.x, a2.y), fminf(a2.z, a2.w)));
    float m3 = wmin(fminf(fminf(a3.x, a3.y), fminf(a3.z, a3.w)));
    if (l == 0) {
        redMin[p * 8 + w1 * 4 + 0] = m0;
        redMin[p * 8 + w1 * 4 + 1] = m1;
        redMin[p * 8 + w1 * 4 + 2] = m2;
        redMin[p * 8 + w1 * 4 + 3] = m3;
    }
    __syncthreads();
    float M0 = fminf(redMin[p * 8 + 0], redMin[p * 8 + 4 + 0]);
    float M1 = fminf(redMin[p * 8 + 1], redMin[p * 8 + 4 + 1]);
    float M2 = fminf(redMin[p * 8 + 2], redMin[p * 8 + 4 + 2]);
    float M3 = fminf(redMin[p * 8 + 3], redMin[p * 8 + 4 + 3]);

    // min L1 == min d^2 (d >= 0) -> exact max-subtraction, args <= 0
    float M0s = M0 * M0, M1s = M1 * M1, M2s = M2 * M2, M3s = M3 * M3;
    float e00 = __expf(0.5f * (M0s - a0.x * a0.x));
    float e01 = __expf(0.5f * (M0s - a0.y * a0.y));
    float e02 = __expf(0.5f * (M0s - a0.z * a0.z));
    float e03 = __expf(0.5f * (M0s - a0.w * a0.w));
    float e10 = __expf(0.5f * (M1s - a1.x * a1.x));
    float e11 = __expf(0.5f * (M1s - a1.y * a1.y));
    float e12 = __expf(0.5f * (M1s - a1.z * a1.z));
    float e13 = __expf(0.5f * (M1s - a1.w * a1.w));
    float e20 = __expf(0.5f * (M2s - a2.x * a2.x));
    float e21 = __expf(0.5f * (M2s - a2.y * a2.y));
    float e22 = __expf(0.5f * (M2s - a2.z * a2.z));
    float e23 = __expf(0.5f * (M2s - a2.w * a2.w));
    float e30 = __expf(0.5f * (M3s - a3.x * a3.x));
    float e31 = __expf(0.5f * (M3s - a3.y * a3.y));
    float e32 = __expf(0.5f * (M3s - a3.z * a3.z));
    float e33 = __expf(0.5f * (M3s - a3.w * a3.w));

    float s0 = wsum((e00 + e01) + (e02 + e03));
    float s1 = wsum((e10 + e11) + (e12 + e13));
    float s2 = wsum((e20 + e21) + (e22 + e23));
    float s3 = wsum((e30 + e31) + (e32 + e33));
    if (l == 0) {
        redSum[p * 8 + w1 * 4 + 0] = s0;
        redSum[p * 8 + w1 * 4 + 1] = s1;
        redSum[p * 8 + w1 * 4 + 2] = s2;
        redSum[p * 8 + w1 * 4 + 3] = s3;
    }
    __syncthreads();
    float i0 = 1.0f / (redSum[p * 8 + 0] + redSum[p * 8 + 4 + 0]);
    float i1 = 1.0f / (redSum[p * 8 + 1] + redSum[p * 8 + 4 + 1]);
    float i2 = 1.0f / (redSum[p * 8 + 2] + redSum[p * 8 + 4 + 2]);
    float i3 = 1.0f / (redSum[p * 8 + 3] + redSum[p * 8 + 4 + 3]);

    float* o0 = out + (size_t)(rowBase + 0) * NCELLS + 4 * L;
    float* o1 = out + (size_t)(rowBase + 1) * NCELLS + 4 * L;
    float* o2 = out + (size_t)(rowBase + 2) * NCELLS + 4 * L;
    float* o3 = out + (size_t)(rowBase + 3) * NCELLS + 4 * L;
    *(float4*)o0 = make_float4(e00 * i0, e01 * i0, e02 * i0, e03 * i0);
    *(float4*)o1 = make_float4(e10 * i1, e11 * i1, e12 * i1, e13 * i1);
    *(float4*)o2 = make_float4(e20 * i2, e21 * i2, e22 * i2, e23 * i2);
    *(float4*)o3 = make_float4(e30 * i3, e31 * i3, e32 * i3, e33 * i3);
}

extern "C" void kernel_launch(void* const* d_in, const int* in_sizes, int n_in,
                              void* d_out, int out_size, void* d_ws, size_t ws_size,
                              hipStream_t stream)
{
    const float* x  = (const float*)d_in[0];   // (8192, 64) fp32
    const float* pc = (const float*)d_in[1];   // (512, 64) fp32
    float* out = (float*)d_out;                // (8192, 512) fp32
    placecells_kernel<<<dim3(NROWS / ROWS_PER_BLOCK), dim3(1024), 0, stream>>>(x, pc, out);
}